// Round 7
// baseline (289.647 us; speedup 1.0000x reference)
//
#include <hip/hip_runtime.h>

// MetaPolicyTransformer: B=65536,T=20,M=4,D=4,L=3,H=2,FF=16,S=5. N=B*T seqs.
// R13 = R11 body (best: 127.4us, bit-identical math) + persistent blocks
// (1280 = 5/CU; removes ramp/drain of 5120 short 5.4us blocks) + FULL layer
// unroll (R9's persistent test was confounded by rolled loop, -6% busy) +
// software-pipelined INPUT PREFETCH (next seq's 2 dwordx4 issued at iter top,
// consumed ~13k cyc later -> input latency never exposed).
// Model (R12 diagnostic): kernel is at ~46% of f32 vector peak with a ~60%
// 2-MAC instruction mix => ~85% of issue-mix roofline; dot2/VOP3P class is
// full-rate (f32-scalar swap was a wash). Remaining headroom = the ~15%
// non-busy time. Pre-committed: if flat, declare roofline.
// R11 body: bo folded into b1'/b2'; packed-e attention (den via dot2(one2),
// PV via 2 dot2 + e4 seed); layer-0 cls-row qkv precomputed by prep; FFN
// hidden via v_pk_fma_f16 + v_pk_max_f16; exp2-domain scores (log2e/sqrt2
// folded into Wk/bqkv_k); no softmax max-subtract (bounded; validated R4).

typedef _Float16 h2 __attribute__((ext_vector_type(2)));

// d_ws word layout (4-byte words; fp32 or half2 per word)
enum {
  WF_CLS  = 0,    // 4   fp32: cls + PE row 0 prefolded
  WF_BQKV = 4,    // 36  fp32 biases, k-part pre-scaled by log2e/sqrt2
  WF_BO   = 40,   // 12  (written by prep; main no longer reads it)
  WF_B2   = 52,   // 12  b2' = b2 + bo (folded)
  H_B1    = 64,   // 24  half2: (l,p) = b1'[2p],b1'[2p+1], b1' = b1 + W1@bo
  H_QKV   = 88,   // 72  half2: (l,row j,pair p) Wqkv[j][2p],[2p+1]; k rows scaled
  H_WO    = 160,  // 24  half2: (l,i,p)
  H_W1    = 184,  // 96  half2 PAIR-MAJOR: (l,p,d) = (W1[2p][d], W1[2p+1][d])
  H_W2    = 280,  // 96  half2: (l,i,fpair p) W2[i][2p],[2p+1]
  WF_QKV0 = 376,  // 12  fp32: layer-0 cls-row q[4] | k[4] (FS-scaled) | v[4]
  WF_FLAG = 388,  // int: 1 if regional_states fp32
  WF_TOTAL = 389
};

__device__ __forceinline__ float bf2f(unsigned short u) {
  unsigned int x = ((unsigned int)u) << 16;
  float f;
  __builtin_memcpy(&f, &x, 4);
  return f;
}

__device__ __forceinline__ bool is_bf16_packed(const unsigned int* w) {
  int pass = 0;
#pragma unroll
  for (int i = 0; i < 16; ++i) {
    unsigned int lo = w[i] & 0xFFFFu;
    unsigned int e = (lo >> 7) & 0xFFu;
    if (lo == 0u || (e >= 90u && e <= 140u)) ++pass;
  }
  return pass >= 15;
}

__device__ __forceinline__ float dot2(h2 a, h2 b, float c) {
#if __has_builtin(__builtin_amdgcn_fdot2)
  return __builtin_amdgcn_fdot2(a, b, c, false);
#else
  return fmaf((float)a.x, (float)b.x, fmaf((float)a.y, (float)b.y, c));
#endif
}

__device__ __forceinline__ h2 pk(float a, float b) {
  // v_cvt_pkrtz_f16_f32; builtin returns __fp16v2 — bitcast to _Float16v2
  auto t = __builtin_amdgcn_cvt_pkrtz(a, b);
  h2 r;
  __builtin_memcpy(&r, &t, sizeof(r));
  return r;
}

__device__ __forceinline__ h2 relu2(h2 a) {
  h2 z = {(_Float16)0.0f, (_Float16)0.0f};
#if __has_builtin(__builtin_elementwise_max)
  return __builtin_elementwise_max(a, z);  // v_pk_max_f16
#else
  h2 r;
  r.x = a.x > z.x ? a.x : z.x;
  r.y = a.y > z.y ? a.y : z.y;
  return r;
#endif
}

__device__ __forceinline__ float fexp2(float x) {
#if __has_builtin(__builtin_amdgcn_exp2f)
  return __builtin_amdgcn_exp2f(x);
#else
  return __builtin_exp2f(x);
#endif
}

// ---- prep: sniff dtypes, build fp32-bias + half2-weight tables in d_ws.
// Runs every call (d_ws re-poisoned before each timed launch). ----
__global__ void mpt_prep(const void* __restrict__ cls,
                         const void* __restrict__ Wqkv,
                         const void* __restrict__ bqkv,
                         const void* __restrict__ Wo,
                         const void* __restrict__ bo,
                         const void* __restrict__ W1,
                         const void* __restrict__ b1,
                         const void* __restrict__ W2,
                         const void* __restrict__ b2,
                         const void* __restrict__ xin,
                         float* __restrict__ wf) {
  const bool wbf = is_bf16_packed((const unsigned int*)Wqkv);
  const bool xbf = is_bf16_packed((const unsigned int*)xin);
  // log2(e)/sqrt(2): folds the 1/sqrt(hd) score scale and exp->exp2.
  const float FS = 1.44269504088896341f * 0.70710678118654752f;

  for (int w = threadIdx.x; w < WF_TOTAL; w += 256) {
    if (w == WF_FLAG) { ((int*)wf)[w] = xbf ? 0 : 1; continue; }

    auto g = [&](const void* src, int idx) -> float {
      return wbf ? bf2f(((const unsigned short*)src)[idx])
                 : ((const float*)src)[idx];
    };

    if (w >= WF_QKV0) {  // layer-0 cls-row qkv constants (j = row 0..11)
      int j = w - WF_QKV0;
      float acc = g(bqkv, j);
#pragma unroll
      for (int d = 0; d < 4; ++d) {
        float xc = g(cls, d) + ((d & 1) ? 1.0f : 0.0f);  // cls + PE row0
        acc = fmaf(g(Wqkv, j * 4 + d), xc, acc);
      }
      if (j >= 4 && j < 8) acc *= FS;  // k rows in log2/sqrt2 domain
      wf[w] = acc;
      continue;
    }

    if (w < H_B1) {  // fp32 region
      float val;
      if (w < WF_BQKV) {                       // cls + PE row0 {0,1,0,1}
        val = g(cls, w) + ((w & 1) ? 1.0f : 0.0f);
      } else if (w < WF_BO) {                  // bqkv, scale k rows
        int t = w - WF_BQKV;
        val = g(bqkv, t);
        int j = t % 12;
        if (j >= 4 && j < 8) val *= FS;
      } else if (w < WF_B2) {
        val = g(bo, w - WF_BO);                // raw bo (unused by main now)
      } else {
        int t = w - WF_B2;                     // b2' = b2 + bo (bo fold)
        val = g(b2, t) + g(bo, t);
      }
      wf[w] = val;
    } else {  // half2 regions
      if (w < H_QKV) {           // b1' pairs: l*8 + p -> b1+W1@bo for 2p,2p+1
        int t = w - H_B1, l = t / 8, p = t % 8;
        int f0 = 2 * p, f1 = 2 * p + 1;
        float v0 = g(b1, l * 16 + f0), v1 = g(b1, l * 16 + f1);
#pragma unroll
        for (int d = 0; d < 4; ++d) {
          float bod = g(bo, l * 4 + d);
          v0 = fmaf(g(W1, l * 64 + f0 * 4 + d), bod, v0);
          v1 = fmaf(g(W1, l * 64 + f1 * 4 + d), bod, v1);
        }
        ((h2*)wf)[w] = pk(v0, v1);
      } else if (w < H_WO) {     // Wqkv: l*48 + j*4 + p*2
        int t = w - H_QKV, l = t / 24, j = (t % 24) / 2, p = t & 1;
        int base = l * 48 + j * 4 + p * 2;
        float s = (j >= 4 && j < 8) ? FS : 1.0f;
        ((h2*)wf)[w] = pk(g(Wqkv, base) * s, g(Wqkv, base + 1) * s);
      } else if (w < H_W1) {     // Wo: l*16 + i*4 + p*2
        int t = w - H_WO, l = t / 8, i = (t % 8) / 2, p = t & 1;
        int base = l * 16 + i * 4 + p * 2;
        ((h2*)wf)[w] = pk(g(Wo, base), g(Wo, base + 1));
      } else if (w < H_W2) {     // W1 pair-major: (l,p,d) -> W1[2p][d], W1[2p+1][d]
        int t = w - H_W1, l = t / 32, p = (t % 32) / 4, d = t % 4;
        int base = l * 64 + 8 * p + d;
        ((h2*)wf)[w] = pk(g(W1, base), g(W1, base + 4));
      } else {                   // W2: l*64 + i*16 + p*2 (pairs along FF)
        int t = w - H_W2, l = t / 32, i = (t % 32) / 8, p = t % 8;
        int base = l * 64 + i * 16 + p * 2;
        ((h2*)wf)[w] = pk(g(W2, base), g(W2, base + 1));
      }
    }
  }
}

// ---- main: persistent blocks; each thread grid-strides over sequences with
// next-sequence input PREFETCH. x state fp32 in registers; linear ops via
// fdot2; FFN hidden via pk_fma_f16. Layer loop FULLY UNROLLED. ----
__global__ __launch_bounds__(256) void mpt_main(
    const void* __restrict__ xin,   // (N,16) fp32 (or bf16; flag decides)
    const float* __restrict__ wf,   // prepped tables in d_ws
    float* __restrict__ out,        // [N*4 F_g | N*16 subregion] fp32
    int N) {
  const int n0 = blockIdx.x * 256 + threadIdx.x;
  if (n0 >= N) return;
  const int stride = gridDim.x * 256;

  const int xf32 = ((const int*)wf)[WF_FLAG];  // wave-uniform
  const h2* hw = (const h2*)wf;                // word-indexed half2 view

  // PE rows 1..4 (row 0 prefolded into cls by prep)
  const float pe[4][4] = {
    { 0.8414709848078965f, 0.5403023058681398f, 0.0099998333341667f, 0.9999500004166653f },
    { 0.9092974268256817f,-0.4161468365471424f, 0.0199986666933331f, 0.9998000066665778f },
    { 0.1411200080598672f,-0.9899924966004454f, 0.0299955002024957f, 0.9995500337489875f },
    {-0.7568024953079283f,-0.6536436208636119f, 0.0399893341866342f, 0.9992001066609779f }
  };

  const h2 one2 = pk(1.0f, 1.0f);  // for den-sum via dot2

  struct alignas(16) U8 { unsigned short v[8]; };
  // prefetch registers (current sequence's raw input, loaded one iter ahead)
  float4 pf[4];
  U8 pb[2];
  if (xf32) {
    const float4* p = reinterpret_cast<const float4*>((const float*)xin + (size_t)n0 * 16);
#pragma unroll
    for (int r = 0; r < 4; ++r) pf[r] = p[r];
  } else {
    const U8* p = reinterpret_cast<const U8*>((const unsigned short*)xin + (size_t)n0 * 16);
    pb[0] = p[0]; pb[1] = p[1];
  }

#pragma unroll 1  // persistent seq loop: one (fully-unrolled) body in I$
  for (int n = n0; n < N; n += stride) {
    // issue NEXT sequence's loads now; consumed ~13k cycles later
    const int nn = n + stride;
    float4 pfN[4];
    U8 pbN[2];
    if (nn < N) {
      if (xf32) {
        const float4* p = reinterpret_cast<const float4*>((const float*)xin + (size_t)nn * 16);
#pragma unroll
        for (int r = 0; r < 4; ++r) pfN[r] = p[r];
      } else {
        const U8* p = reinterpret_cast<const U8*>((const unsigned short*)xin + (size_t)nn * 16);
        pbN[0] = p[0]; pbN[1] = p[1];
      }
    }

    // convert current prefetched input -> x state
    float raw[16];
    if (xf32) {
#pragma unroll
      for (int r = 0; r < 4; ++r) {
        raw[r * 4 + 0] = pf[r].x; raw[r * 4 + 1] = pf[r].y;
        raw[r * 4 + 2] = pf[r].z; raw[r * 4 + 3] = pf[r].w;
      }
    } else {
#pragma unroll
      for (int j = 0; j < 8; ++j) {
        raw[j]     = bf2f(pb[0].v[j]);
        raw[8 + j] = bf2f(pb[1].v[j]);
      }
    }

    float x[5][4];
#pragma unroll
    for (int d = 0; d < 4; ++d) x[0][d] = wf[WF_CLS + d];  // cls+PE0 prefolded
#pragma unroll
    for (int r = 0; r < 4; ++r)
#pragma unroll
      for (int d = 0; d < 4; ++d) x[1 + r][d] = raw[r * 4 + d] + pe[r][d];

#pragma unroll  // FULL unroll: scheduler prefetches next layer's s_loads
    for (int l = 0; l < 3; ++l) {
      const float* bq  = wf + WF_BQKV + l * 12;
      const float* b2  = wf + WF_B2   + l * 4;   // b2' = b2 + bo
      const h2* hb1  = hw + H_B1  + l * 8;   // b1' pairs
      const h2* hq   = hw + H_QKV + l * 24;  // [j*2 + p]
      const h2* hwo  = hw + H_WO  + l * 8;   // [i*2 + p]
      const h2* hw1p = hw + H_W1  + l * 32;  // [p*4 + d]
      const h2* hw2  = hw + H_W2  + l * 32;  // [i*8 + p]

      // pack x rows to half2 pairs (layer 0 row 0 unused: cls consts from prep)
      h2 xh[5][2];
#pragma unroll
      for (int s = 0; s < 5; ++s) {
        if (l == 0 && s == 0) continue;
        xh[s][0] = pk(x[s][0], x[s][1]);
        xh[s][1] = pk(x[s][2], x[s][3]);
      }

      // qkv projection: 2 chained fdot2 per output (k rows pre-scaled)
      float q[5][4], k[5][4], v[5][4];
#pragma unroll
      for (int s = 0; s < 5; ++s) {
        if (l == 0 && s == 0) {  // constant cls row: precomputed by prep
#pragma unroll
          for (int j = 0; j < 4; ++j) {
            q[0][j] = wf[WF_QKV0 + j];
            k[0][j] = wf[WF_QKV0 + 4 + j];
            v[0][j] = wf[WF_QKV0 + 8 + j];
          }
          continue;
        }
#pragma unroll
        for (int j = 0; j < 12; ++j) {
          float a = dot2(xh[s][0], hq[j * 2],
                         dot2(xh[s][1], hq[j * 2 + 1], bq[j]));
          if (j < 4)      q[s][j] = a;
          else if (j < 8) k[s][j - 4] = a;
          else            v[s][j - 8] = a;
        }
      }

      // attention: head h uses dims {2h,2h+1}; exp2-domain scores;
      // e packed to h2; den via dot2(one2); PV per dim via 1 mul + 2 dot2.
      h2 oh[5][2];  // packed attention output per (si, head)
#pragma unroll
      for (int h = 0; h < 2; ++h) {
        const int d0 = 2 * h, d1 = 2 * h + 1;
        h2 qh[5], kh[5];
#pragma unroll
        for (int s = 0; s < 5; ++s) {
          qh[s] = pk(q[s][d0], q[s][d1]);
          kh[s] = pk(k[s][d0], k[s][d1]);
        }
        h2 vp0[2], vp1[2];
        vp0[0] = pk(v[0][d0], v[1][d0]); vp0[1] = pk(v[2][d0], v[3][d0]);
        vp1[0] = pk(v[0][d1], v[1][d1]); vp1[1] = pk(v[2][d1], v[3][d1]);
#pragma unroll
        for (int si = 0; si < 5; ++si) {
          float e0 = fexp2(dot2(qh[si], kh[0], 0.0f));
          float e1 = fexp2(dot2(qh[si], kh[1], 0.0f));
          float e2 = fexp2(dot2(qh[si], kh[2], 0.0f));
          float e3 = fexp2(dot2(qh[si], kh[3], 0.0f));
          float e4 = fexp2(dot2(qh[si], kh[4], 0.0f));
          h2 ep0 = pk(e0, e1), ep1 = pk(e2, e3);
          float den = dot2(ep0, one2, dot2(ep1, one2, e4));
          float inv = __builtin_amdgcn_rcpf(den);
          float a0 = dot2(ep0, vp0[0], dot2(ep1, vp0[1], e4 * v[4][d0]));
          float a1 = dot2(ep0, vp1[0], dot2(ep1, vp1[1], e4 * v[4][d1]));
          oh[si][h] = pk(a0 * inv, a1 * inv);
        }
      }

      // out-proj + residual (bo folded into b1'/b2'), then FFN + residual
#pragma unroll
      for (int s = 0; s < 5; ++s) {
        float nx[4];  // nx' = x + o@Wo^T (true nx minus bo)
#pragma unroll
        for (int i = 0; i < 4; ++i)
          nx[i] = dot2(oh[s][0], hwo[i * 2],
                       dot2(oh[s][1], hwo[i * 2 + 1], x[s][i]));

        h2 xb[4];
        float acc[4];
#pragma unroll
        for (int d = 0; d < 4; ++d) xb[d] = pk(nx[d], nx[d]);
#pragma unroll
        for (int i = 0; i < 4; ++i) acc[i] = b2[i];
#pragma unroll
        for (int p = 0; p < 8; ++p) {
          h2 hc = hb1[p];
#pragma unroll
          for (int d = 0; d < 4; ++d) hc = xb[d] * hw1p[p * 4 + d] + hc;  // v_pk_fma_f16
          h2 hh = relu2(hc);  // v_pk_max_f16
#pragma unroll
          for (int i = 0; i < 4; ++i) acc[i] = dot2(hh, hw2[i * 8 + p], acc[i]);
        }
#pragma unroll
        for (int i = 0; i < 4; ++i) x[s][i] = nx[i] + acc[i];
      }
    }

    // stores (fp32, coalesced dwordx4)
    *reinterpret_cast<float4*>(out + (size_t)n * 4) =
        make_float4(x[0][0], x[0][1], x[0][2], x[0][3]);
    float* sub = out + (size_t)N * 4 + (size_t)n * 16;
#pragma unroll
    for (int r = 0; r < 4; ++r)
      *reinterpret_cast<float4*>(sub + r * 4) =
          make_float4(x[1 + r][0], x[1 + r][1], x[1 + r][2], x[1 + r][3]);

    // rotate prefetch
    if (nn < N) {
      if (xf32) {
#pragma unroll
        for (int r = 0; r < 4; ++r) pf[r] = pfN[r];
      } else {
        pb[0] = pbN[0]; pb[1] = pbN[1];
      }
    }
  }
}

extern "C" void kernel_launch(void* const* d_in, const int* in_sizes, int n_in,
                              void* d_out, int out_size, void* d_ws, size_t ws_size,
                              hipStream_t stream) {
  float* wf = (float*)d_ws;

  mpt_prep<<<1, 256, 0, stream>>>(
      d_in[1], d_in[2], d_in[3], d_in[4], d_in[5],
      d_in[6], d_in[7], d_in[8], d_in[9],
      d_in[0],  // regional_states (dtype sniff)
      wf);

  const int N = in_sizes[0] / 16;  // B*T sequences
  // Persistent grid: 1280 blocks = 5/CU (20 waves/CU); N=1.31M -> exactly 4
  // sequences per thread. Grid-stride handles general N.
  int blocks = (N + 255) / 256;
  if (blocks > 1280) blocks = 1280;
  mpt_main<<<blocks, 256, 0, stream>>>(
      d_in[0], wf, (float*)d_out, N);
}

// Round 8
// 254.050 us; speedup vs baseline: 1.1401x; 1.1401x over previous
//
#include <hip/hip_runtime.h>

// MetaPolicyTransformer: B=65536,T=20,M=4,D=4,L=3,H=2,FF=16,S=5. N=B*T seqs.
// R14 = R11 restored verbatim (best: 127.4us main / 254.6us total).
// Session evidence summary:
//  - Only source-op cuts move time (~30us/1000 ops/seq): R7 FFN pk_fma,
//    R11 {bo-fold, packed-e attention, layer-0 cls-row qkv}.
//  - Instruction-class swaps are null (R12: f32-fma vs dot2 wash) -> issue
//    rate ~2.4 cyc/instr for this mix regardless of class.
//  - Occupancy/persistence attacks on the ~15% idle are null or negative
//    (R8 launch_bounds null; R9 persistent null; R13 persistent+prefetch
//    -28%: issue-work +15% and residency fell to 19.6%).
//  - One-shot 256-thread blocks + FULL layer unroll is the empirical optimum
//    (full unroll buys ~6% busy via cross-layer s_load prefetch).
// Body: bo folded into b1'/b2'; packed-e attention (den via dot2(one2), PV
// via 2 dot2 + e4 seed); layer-0 cls-row qkv precomputed by prep; FFN hidden
// via v_pk_fma_f16 + v_pk_max_f16; exp2-domain scores (log2e/sqrt2 folded
// into Wk/bqkv_k by prep); no softmax max-subtract (bounded; validated R4).

typedef _Float16 h2 __attribute__((ext_vector_type(2)));

// d_ws word layout (4-byte words; fp32 or half2 per word)
enum {
  WF_CLS  = 0,    // 4   fp32: cls + PE row 0 prefolded
  WF_BQKV = 4,    // 36  fp32 biases, k-part pre-scaled by log2e/sqrt2
  WF_BO   = 40,   // 12  (written by prep; main no longer reads it)
  WF_B2   = 52,   // 12  b2' = b2 + bo (folded)
  H_B1    = 64,   // 24  half2: (l,p) = b1'[2p],b1'[2p+1], b1' = b1 + W1@bo
  H_QKV   = 88,   // 72  half2: (l,row j,pair p) Wqkv[j][2p],[2p+1]; k rows scaled
  H_WO    = 160,  // 24  half2: (l,i,p)
  H_W1    = 184,  // 96  half2 PAIR-MAJOR: (l,p,d) = (W1[2p][d], W1[2p+1][d])
  H_W2    = 280,  // 96  half2: (l,i,fpair p) W2[i][2p],[2p+1]
  WF_QKV0 = 376,  // 12  fp32: layer-0 cls-row q[4] | k[4] (FS-scaled) | v[4]
  WF_FLAG = 388,  // int: 1 if regional_states fp32
  WF_TOTAL = 389
};

__device__ __forceinline__ float bf2f(unsigned short u) {
  unsigned int x = ((unsigned int)u) << 16;
  float f;
  __builtin_memcpy(&f, &x, 4);
  return f;
}

__device__ __forceinline__ bool is_bf16_packed(const unsigned int* w) {
  int pass = 0;
#pragma unroll
  for (int i = 0; i < 16; ++i) {
    unsigned int lo = w[i] & 0xFFFFu;
    unsigned int e = (lo >> 7) & 0xFFu;
    if (lo == 0u || (e >= 90u && e <= 140u)) ++pass;
  }
  return pass >= 15;
}

__device__ __forceinline__ float dot2(h2 a, h2 b, float c) {
#if __has_builtin(__builtin_amdgcn_fdot2)
  return __builtin_amdgcn_fdot2(a, b, c, false);
#else
  return fmaf((float)a.x, (float)b.x, fmaf((float)a.y, (float)b.y, c));
#endif
}

__device__ __forceinline__ h2 pk(float a, float b) {
  // v_cvt_pkrtz_f16_f32; builtin returns __fp16v2 — bitcast to _Float16v2
  auto t = __builtin_amdgcn_cvt_pkrtz(a, b);
  h2 r;
  __builtin_memcpy(&r, &t, sizeof(r));
  return r;
}

__device__ __forceinline__ h2 relu2(h2 a) {
  h2 z = {(_Float16)0.0f, (_Float16)0.0f};
#if __has_builtin(__builtin_elementwise_max)
  return __builtin_elementwise_max(a, z);  // v_pk_max_f16
#else
  h2 r;
  r.x = a.x > z.x ? a.x : z.x;
  r.y = a.y > z.y ? a.y : z.y;
  return r;
#endif
}

__device__ __forceinline__ float fexp2(float x) {
#if __has_builtin(__builtin_amdgcn_exp2f)
  return __builtin_amdgcn_exp2f(x);
#else
  return __builtin_exp2f(x);
#endif
}

// ---- prep: sniff dtypes, build fp32-bias + half2-weight tables in d_ws.
// Runs every call (d_ws re-poisoned before each timed launch). ----
__global__ void mpt_prep(const void* __restrict__ cls,
                         const void* __restrict__ Wqkv,
                         const void* __restrict__ bqkv,
                         const void* __restrict__ Wo,
                         const void* __restrict__ bo,
                         const void* __restrict__ W1,
                         const void* __restrict__ b1,
                         const void* __restrict__ W2,
                         const void* __restrict__ b2,
                         const void* __restrict__ xin,
                         float* __restrict__ wf) {
  const bool wbf = is_bf16_packed((const unsigned int*)Wqkv);
  const bool xbf = is_bf16_packed((const unsigned int*)xin);
  // log2(e)/sqrt(2): folds the 1/sqrt(hd) score scale and exp->exp2.
  const float FS = 1.44269504088896341f * 0.70710678118654752f;

  for (int w = threadIdx.x; w < WF_TOTAL; w += 256) {
    if (w == WF_FLAG) { ((int*)wf)[w] = xbf ? 0 : 1; continue; }

    auto g = [&](const void* src, int idx) -> float {
      return wbf ? bf2f(((const unsigned short*)src)[idx])
                 : ((const float*)src)[idx];
    };

    if (w >= WF_QKV0) {  // layer-0 cls-row qkv constants (j = row 0..11)
      int j = w - WF_QKV0;
      float acc = g(bqkv, j);
#pragma unroll
      for (int d = 0; d < 4; ++d) {
        float xc = g(cls, d) + ((d & 1) ? 1.0f : 0.0f);  // cls + PE row0
        acc = fmaf(g(Wqkv, j * 4 + d), xc, acc);
      }
      if (j >= 4 && j < 8) acc *= FS;  // k rows in log2/sqrt2 domain
      wf[w] = acc;
      continue;
    }

    if (w < H_B1) {  // fp32 region
      float val;
      if (w < WF_BQKV) {                       // cls + PE row0 {0,1,0,1}
        val = g(cls, w) + ((w & 1) ? 1.0f : 0.0f);
      } else if (w < WF_BO) {                  // bqkv, scale k rows
        int t = w - WF_BQKV;
        val = g(bqkv, t);
        int j = t % 12;
        if (j >= 4 && j < 8) val *= FS;
      } else if (w < WF_B2) {
        val = g(bo, w - WF_BO);                // raw bo (unused by main now)
      } else {
        int t = w - WF_B2;                     // b2' = b2 + bo (bo fold)
        val = g(b2, t) + g(bo, t);
      }
      wf[w] = val;
    } else {  // half2 regions
      if (w < H_QKV) {           // b1' pairs: l*8 + p -> b1+W1@bo for 2p,2p+1
        int t = w - H_B1, l = t / 8, p = t % 8;
        int f0 = 2 * p, f1 = 2 * p + 1;
        float v0 = g(b1, l * 16 + f0), v1 = g(b1, l * 16 + f1);
#pragma unroll
        for (int d = 0; d < 4; ++d) {
          float bod = g(bo, l * 4 + d);
          v0 = fmaf(g(W1, l * 64 + f0 * 4 + d), bod, v0);
          v1 = fmaf(g(W1, l * 64 + f1 * 4 + d), bod, v1);
        }
        ((h2*)wf)[w] = pk(v0, v1);
      } else if (w < H_WO) {     // Wqkv: l*48 + j*4 + p*2
        int t = w - H_QKV, l = t / 24, j = (t % 24) / 2, p = t & 1;
        int base = l * 48 + j * 4 + p * 2;
        float s = (j >= 4 && j < 8) ? FS : 1.0f;
        ((h2*)wf)[w] = pk(g(Wqkv, base) * s, g(Wqkv, base + 1) * s);
      } else if (w < H_W1) {     // Wo: l*16 + i*4 + p*2
        int t = w - H_WO, l = t / 8, i = (t % 8) / 2, p = t & 1;
        int base = l * 16 + i * 4 + p * 2;
        ((h2*)wf)[w] = pk(g(Wo, base), g(Wo, base + 1));
      } else if (w < H_W2) {     // W1 pair-major: (l,p,d) -> W1[2p][d], W1[2p+1][d]
        int t = w - H_W1, l = t / 32, p = (t % 32) / 4, d = t % 4;
        int base = l * 64 + 8 * p + d;
        ((h2*)wf)[w] = pk(g(W1, base), g(W1, base + 4));
      } else {                   // W2: l*64 + i*16 + p*2 (pairs along FF)
        int t = w - H_W2, l = t / 32, i = (t % 32) / 8, p = t % 8;
        int base = l * 64 + i * 16 + p * 2;
        ((h2*)wf)[w] = pk(g(W2, base), g(W2, base + 1));
      }
    }
  }
}

// ---- main: one thread per sequence; x state fp32 in registers; linear ops
// via fdot2 (fp16 operands, fp32 accumulate); FFN hidden via pk_fma_f16;
// attention PV/den via packed-e dot2. Layer loop FULLY UNROLLED. ----
__global__ __launch_bounds__(256) void mpt_main(
    const void* __restrict__ xin,   // (N,16) fp32 (or bf16; flag decides)
    const float* __restrict__ wf,   // prepped tables in d_ws
    float* __restrict__ out,        // [N*4 F_g | N*16 subregion] fp32
    int N) {
  const int n = blockIdx.x * 256 + threadIdx.x;
  if (n >= N) return;

  const int xf32 = ((const int*)wf)[WF_FLAG];  // wave-uniform
  const h2* hw = (const h2*)wf;                // word-indexed half2 view

  // PE rows 1..4 (row 0 prefolded into cls by prep)
  const float pe[4][4] = {
    { 0.8414709848078965f, 0.5403023058681398f, 0.0099998333341667f, 0.9999500004166653f },
    { 0.9092974268256817f,-0.4161468365471424f, 0.0199986666933331f, 0.9998000066665778f },
    { 0.1411200080598672f,-0.9899924966004454f, 0.0299955002024957f, 0.9995500337489875f },
    {-0.7568024953079283f,-0.6536436208636119f, 0.0399893341866342f, 0.9992001066609779f }
  };

  float raw[16];
  if (xf32) {
    const float4* pf = reinterpret_cast<const float4*>((const float*)xin + (size_t)n * 16);
#pragma unroll
    for (int r = 0; r < 4; ++r) {
      float4 t = pf[r];
      raw[r * 4 + 0] = t.x; raw[r * 4 + 1] = t.y;
      raw[r * 4 + 2] = t.z; raw[r * 4 + 3] = t.w;
    }
  } else {
    struct alignas(16) U8 { unsigned short v[8]; };
    const U8* p = reinterpret_cast<const U8*>((const unsigned short*)xin + (size_t)n * 16);
    U8 a0 = p[0], a1 = p[1];
#pragma unroll
    for (int j = 0; j < 8; ++j) {
      raw[j]     = bf2f(a0.v[j]);
      raw[8 + j] = bf2f(a1.v[j]);
    }
  }

  float x[5][4];
#pragma unroll
  for (int d = 0; d < 4; ++d) x[0][d] = wf[WF_CLS + d];  // cls+PE0 prefolded
#pragma unroll
  for (int r = 0; r < 4; ++r)
#pragma unroll
    for (int d = 0; d < 4; ++d) x[1 + r][d] = raw[r * 4 + d] + pe[r][d];

  const h2 one2 = pk(1.0f, 1.0f);  // for den-sum via dot2

#pragma unroll  // FULL unroll: lets the scheduler prefetch next layer's s_loads
  for (int l = 0; l < 3; ++l) {
    const float* bq  = wf + WF_BQKV + l * 12;
    const float* b2  = wf + WF_B2   + l * 4;   // b2' = b2 + bo
    const h2* hb1  = hw + H_B1  + l * 8;   // b1' pairs
    const h2* hq   = hw + H_QKV + l * 24;  // [j*2 + p]
    const h2* hwo  = hw + H_WO  + l * 8;   // [i*2 + p]
    const h2* hw1p = hw + H_W1  + l * 32;  // [p*4 + d] = (W1[2p][d], W1[2p+1][d])
    const h2* hw2  = hw + H_W2  + l * 32;  // [i*8 + p]

    // pack x rows to half2 pairs (layer 0 row 0 unused: cls consts from prep)
    h2 xh[5][2];
#pragma unroll
    for (int s = 0; s < 5; ++s) {
      if (l == 0 && s == 0) continue;
      xh[s][0] = pk(x[s][0], x[s][1]);
      xh[s][1] = pk(x[s][2], x[s][3]);
    }

    // qkv projection: 2 chained fdot2 per output (k rows pre-scaled, log2 units)
    float q[5][4], k[5][4], v[5][4];
#pragma unroll
    for (int s = 0; s < 5; ++s) {
      if (l == 0 && s == 0) {  // constant cls row: precomputed by prep
#pragma unroll
        for (int j = 0; j < 4; ++j) {
          q[0][j] = wf[WF_QKV0 + j];
          k[0][j] = wf[WF_QKV0 + 4 + j];
          v[0][j] = wf[WF_QKV0 + 8 + j];
        }
        continue;
      }
#pragma unroll
      for (int j = 0; j < 12; ++j) {
        float a = dot2(xh[s][0], hq[j * 2],
                       dot2(xh[s][1], hq[j * 2 + 1], bq[j]));
        if (j < 4)      q[s][j] = a;
        else if (j < 8) k[s][j - 4] = a;
        else            v[s][j - 8] = a;
      }
    }

    // attention: head h uses dims {2h,2h+1}; score = fdot2(qh,kh), exp2 domain.
    // e packed to h2; den via dot2(one2); PV per dim via 1 mul + 2 dot2.
    h2 oh[5][2];  // packed attention output: oh[si][h] = (o[d0], o[d1]) scaled
#pragma unroll
    for (int h = 0; h < 2; ++h) {
      const int d0 = 2 * h, d1 = 2 * h + 1;
      h2 qh[5], kh[5];
#pragma unroll
      for (int s = 0; s < 5; ++s) {
        qh[s] = pk(q[s][d0], q[s][d1]);
        kh[s] = pk(k[s][d0], k[s][d1]);
      }
      // V pre-packed along sj (pairs 0-1, 2-3; row 4 handled via seed fma)
      h2 vp0[2], vp1[2];
      vp0[0] = pk(v[0][d0], v[1][d0]); vp0[1] = pk(v[2][d0], v[3][d0]);
      vp1[0] = pk(v[0][d1], v[1][d1]); vp1[1] = pk(v[2][d1], v[3][d1]);
#pragma unroll
      for (int si = 0; si < 5; ++si) {
        float e0 = fexp2(dot2(qh[si], kh[0], 0.0f));
        float e1 = fexp2(dot2(qh[si], kh[1], 0.0f));
        float e2 = fexp2(dot2(qh[si], kh[2], 0.0f));
        float e3 = fexp2(dot2(qh[si], kh[3], 0.0f));
        float e4 = fexp2(dot2(qh[si], kh[4], 0.0f));
        h2 ep0 = pk(e0, e1), ep1 = pk(e2, e3);
        float den = dot2(ep0, one2, dot2(ep1, one2, e4));
        float inv = __builtin_amdgcn_rcpf(den);
        float a0 = dot2(ep0, vp0[0], dot2(ep1, vp0[1], e4 * v[4][d0]));
        float a1 = dot2(ep0, vp1[0], dot2(ep1, vp1[1], e4 * v[4][d1]));
        oh[si][h] = pk(a0 * inv, a1 * inv);
      }
    }

    // out-proj + residual (bo folded into b1'/b2'), then FFN + residual
#pragma unroll
    for (int s = 0; s < 5; ++s) {
      float nx[4];  // nx' = x + o@Wo^T (true nx minus bo)
#pragma unroll
      for (int i = 0; i < 4; ++i)
        nx[i] = dot2(oh[s][0], hwo[i * 2],
                     dot2(oh[s][1], hwo[i * 2 + 1], x[s][i]));

      // broadcast pairs of nx for pk_fma; acc fp32 via dot2
      h2 xb[4];
      float acc[4];
#pragma unroll
      for (int d = 0; d < 4; ++d) xb[d] = pk(nx[d], nx[d]);
#pragma unroll
      for (int i = 0; i < 4; ++i) acc[i] = b2[i];
#pragma unroll
      for (int p = 0; p < 8; ++p) {
        h2 hc = hb1[p];
#pragma unroll
        for (int d = 0; d < 4; ++d) hc = xb[d] * hw1p[p * 4 + d] + hc;  // v_pk_fma_f16
        h2 hh = relu2(hc);  // v_pk_max_f16
#pragma unroll
        for (int i = 0; i < 4; ++i) acc[i] = dot2(hh, hw2[i * 8 + p], acc[i]);
      }
#pragma unroll
      for (int i = 0; i < 4; ++i) x[s][i] = nx[i] + acc[i];
    }
  }

  // stores (fp32, coalesced dwordx4)
  *reinterpret_cast<float4*>(out + (size_t)n * 4) =
      make_float4(x[0][0], x[0][1], x[0][2], x[0][3]);
  float* sub = out + (size_t)N * 4 + (size_t)n * 16;
#pragma unroll
  for (int r = 0; r < 4; ++r)
    *reinterpret_cast<float4*>(sub + r * 4) =
        make_float4(x[1 + r][0], x[1 + r][1], x[1 + r][2], x[1 + r][3]);
}

extern "C" void kernel_launch(void* const* d_in, const int* in_sizes, int n_in,
                              void* d_out, int out_size, void* d_ws, size_t ws_size,
                              hipStream_t stream) {
  float* wf = (float*)d_ws;

  mpt_prep<<<1, 256, 0, stream>>>(
      d_in[1], d_in[2], d_in[3], d_in[4], d_in[5],
      d_in[6], d_in[7], d_in[8], d_in[9],
      d_in[0],  // regional_states (dtype sniff)
      wf);

  const int N = in_sizes[0] / 16;  // B*T sequences
  mpt_main<<<(N + 255) / 256, 256, 0, stream>>>(
      d_in[0], wf, (float*)d_out, N);
}